// Round 12
// baseline (384.197 us; speedup 1.0000x reference)
//
#include <hip/hip_runtime.h>
#include <hip/hip_bf16.h>
#include <hip/hip_cooperative_groups.h>

namespace cg = cooperative_groups;

// Problem constants: B=8, G=2048, K=32, N=6, C=64; fourier_B is (7,32)
// out: (B, 128, G) float32
//
// Algebraic simplifications (validated):
//  1) up/down == mean_k(knn_f) since e_x is constant over k, so
//     kl_raw = 2*mean_k(sin^5/cos^5(2*pi*x)).
//  2) x = fB . [p, p x n, p.n] is linear in p:
//     x = e0*p0 + e1*p1 + e2*p2 with per-channel e precomputed from fB and n.
//
// Round 12: round-9 body (best, 21.5us) + cooperative fusion WITH CHECKED
// FALLBACK. If hipLaunchCooperativeKernel is rejected, launch the proven
// two-kernel path instead (identical math). Fusion removes pass2's 12.6 MB
// round-trip and one launch gap; g-axis norm via atomicAdd partials + grid
// sync + in-LDS rescale.

#if __has_builtin(__builtin_amdgcn_fractf)
  #define FRACT(x) __builtin_amdgcn_fractf(x)
#else
  #define FRACT(x) ((x) - floorf(x))
#endif

// ---- shared body: computes this block's klbuf tile (8 bg) ------------------
// klbuf rows 0..63 = kl_raw, rows 64..127 = lc_line.
__device__ __forceinline__ void compute_tile(
    const float* __restrict__ lc_x, const float* __restrict__ knn_x,
    const float* __restrict__ fB, int bg0,
    float (*lcbuf)[128], float (*knbuf)[384], float (*klbuf)[9])
{
    const int wave = threadIdx.x >> 6;
    const int lane = threadIdx.x & 63;
    const int half = lane >> 5;                 // 0: even k, 1: odd k
    const int jj   = lane & 31;                 // channel

    // fourier_B column for this lane's channel
    const float fb0 = fB[0*32 + jj];
    const float fb1 = fB[1*32 + jj];
    const float fb2 = fB[2*32 + jj];
    const float fb3 = fB[3*32 + jj];
    const float fb4 = fB[4*32 + jj];
    const float fb5 = fB[5*32 + jj];
    const float fb6 = fB[6*32 + jj];

    // coalesced staging: 2 float4 loads per lane, wave-local LDS
    {
        const float4* lcsrc = (const float4*)(lc_x  + (size_t)(bg0 + wave * 2) * 64);
        const float4* knsrc = (const float4*)(knn_x + (size_t)(bg0 + wave * 2) * 192);
        float4* lcb4 = (float4*)&lcbuf[wave][0];   // 32 float4
        float4* knb4 = (float4*)&knbuf[wave][0];   // 96 float4
        if (lane < 32) lcb4[lane]      = lcsrc[lane];
        else           knb4[lane + 32] = knsrc[lane + 32];
        knb4[lane] = knsrc[lane];
    }
    asm volatile("s_waitcnt vmcnt(0) lgkmcnt(0)" ::: "memory");

    #pragma unroll
    for (int i = 0; i < 2; ++i) {
        const int col = wave * 2 + i;
        const float* lcr = &lcbuf[wave][i * 64];
        const float* knr = &knbuf[wave][i * 192];

        const float n0 = lcr[3];
        const float n1 = lcr[4];
        const float n2 = lcr[5];

        const float myv = lcr[lane];
        float ssum = myv * myv;
        #pragma unroll
        for (int off = 32; off; off >>= 1) ssum += __shfl_xor(ssum, off, 64);
        klbuf[64 + lane][col] = myv / sqrtf(ssum);

        const float e0 = fmaf(fb6, n0, fmaf(fb5,  n1, fmaf(fb4, -n2, fb0)));
        const float e1 = fmaf(fb6, n1, fmaf(fb5, -n0, fmaf(fb3,  n2, fb1)));
        const float e2 = fmaf(fb6, n2, fmaf(fb4,  n0, fmaf(fb3, -n1, fb2)));

        float accS0 = 0.f, accS1 = 0.f, accC0 = 0.f, accC1 = 0.f;
        const float* myk = knr + half * 6;              // k = 2*t + half
        #pragma unroll
        for (int t = 0; t < 16; ++t) {
            const float p0 = myk[t * 12 + 3];
            const float p1 = myk[t * 12 + 4];
            const float p2 = myk[t * 12 + 5];
            const float x = fmaf(e2, p2, fmaf(e1, p1, e0 * p0));
            const float ts = FRACT(x);
            const float tc = FRACT(x + 0.25f);
            const float s  = __builtin_amdgcn_sinf(ts);
            const float cq = __builtin_amdgcn_sinf(tc);
            const float s2 = s * s,   s4 = s2 * s2;
            const float q2 = cq * cq, q4 = q2 * q2;
            if (t & 1) { accS1 = fmaf(s4, s, accS1); accC1 = fmaf(q4, cq, accC1); }
            else       { accS0 = fmaf(s4, s, accS0); accC0 = fmaf(q4, cq, accC0); }
        }
        const float aS = accS0 + accS1;
        const float aC = accC0 + accC1;
        const float totS = aS + __shfl_xor(aS, 32, 64);
        const float totC = aC + __shfl_xor(aC, 32, 64);
        klbuf[lane][col] = (half ? totC : totS) * 0.0625f;
    }

    __syncthreads();
}

// ---- fused cooperative kernel ----------------------------------------------
__global__ __launch_bounds__(256, 8) void line_fused(
    const float* __restrict__ lc_x, const float* __restrict__ knn_x,
    const float* __restrict__ fB, float* __restrict__ out,
    float* __restrict__ ws)             // 512 floats, zeroed per launch
{
    const int sbid = (blockIdx.x & 7) * 256 + (blockIdx.x >> 3);
    const int bg0  = sbid * 8;
    const int b    = bg0 >> 11;
    const int g0   = bg0 & 2047;

    __shared__ __align__(16) float lcbuf[4][128];
    __shared__ __align__(16) float knbuf[4][384];
    __shared__ float klbuf[128][9];

    compute_tile(lc_x, knn_x, fB, bg0, lcbuf, knbuf, klbuf);

    // block-partial Sum(kl^2) per channel -> device atomic accumulate
    {
        const int c = threadIdx.x >> 2;       // 0..63, 4 threads per channel
        const float v0 = klbuf[c][(threadIdx.x & 3) * 2 + 0];
        const float v1 = klbuf[c][(threadIdx.x & 3) * 2 + 1];
        float v = v0 * v0 + v1 * v1;
        v += __shfl_xor(v, 1, 64);
        v += __shfl_xor(v, 2, 64);
        if ((threadIdx.x & 3) == 0) atomicAdd(&ws[b * 64 + c], v);
    }

    // store lc_line rows (64..127) while the grid catches up
    if (threadIdx.x < 128) {
        const int c  = 64 + (threadIdx.x >> 1);
        const int j0 = (threadIdx.x & 1) * 4;
        const float4 o = make_float4(klbuf[c][j0], klbuf[c][j0+1],
                                     klbuf[c][j0+2], klbuf[c][j0+3]);
        *(float4*)(out + ((size_t)b * 128 + c) * 2048 + g0 + j0) = o;
    }

    __threadfence();
    cg::this_grid().sync();

    // normalize own tile (still in LDS) and store kl rows (0..63)
    if (threadIdx.x < 128) {
        const int c  = threadIdx.x >> 1;
        const int j0 = (threadIdx.x & 1) * 4;
        const float rn = 1.0f / sqrtf(ws[b * 64 + c]);
        float o[4];
        #pragma unroll
        for (int q = 0; q < 4; ++q)
            o[q] = fmaf(klbuf[c][j0 + q], rn, -klbuf[64 + c][j0 + q]);
        *(float4*)(out + ((size_t)b * 128 + c) * 2048 + g0 + j0) =
            make_float4(o[0], o[1], o[2], o[3]);
    }
}

// ---- fallback two-kernel path (round 9, proven 21.5us) ---------------------
__global__ __launch_bounds__(256, 8) void line_pass1(
    const float* __restrict__ lc_x, const float* __restrict__ knn_x,
    const float* __restrict__ fB, float* __restrict__ out)
{
    const int sbid = (blockIdx.x & 7) * 256 + (blockIdx.x >> 3);
    const int bg0  = sbid * 8;
    const int b    = bg0 >> 11;
    const int g0   = bg0 & 2047;

    __shared__ __align__(16) float lcbuf[4][128];
    __shared__ __align__(16) float knbuf[4][384];
    __shared__ float klbuf[128][9];

    compute_tile(lc_x, knn_x, fB, bg0, lcbuf, knbuf, klbuf);

    const int c  = threadIdx.x >> 1;
    const int j0 = (threadIdx.x & 1) * 4;
    const float4 o = make_float4(klbuf[c][j0], klbuf[c][j0+1],
                                 klbuf[c][j0+2], klbuf[c][j0+3]);
    *(float4*)(out + ((size_t)b * 128 + c) * 2048 + g0 + j0) = o;
}

__global__ __launch_bounds__(256) void line_pass2(float* __restrict__ out)
{
    const int b = blockIdx.x >> 6;
    const int c = blockIdx.x & 63;
    float4*       kl = (float4*)(out + ((size_t)b * 128 + c) * 2048);
    const float4* ll = (const float4*)(out + ((size_t)b * 128 + 64 + c) * 2048);
    const int t = threadIdx.x;

    const float4 v0 = kl[t];
    const float4 v1 = kl[t + 256];
    const float4 l0 = ll[t];
    const float4 l1 = ll[t + 256];

    float ss = v0.x*v0.x + v0.y*v0.y + v0.z*v0.z + v0.w*v0.w
             + v1.x*v1.x + v1.y*v1.y + v1.z*v1.z + v1.w*v1.w;
    #pragma unroll
    for (int off = 32; off; off >>= 1) ss += __shfl_xor(ss, off, 64);

    __shared__ float wsum[4];
    if ((t & 63) == 0) wsum[t >> 6] = ss;
    __syncthreads();
    const float tot = wsum[0] + wsum[1] + wsum[2] + wsum[3];
    const float rn  = 1.0f / sqrtf(tot);

    kl[t]       = make_float4(fmaf(v0.x, rn, -l0.x), fmaf(v0.y, rn, -l0.y),
                              fmaf(v0.z, rn, -l0.z), fmaf(v0.w, rn, -l0.w));
    kl[t + 256] = make_float4(fmaf(v1.x, rn, -l1.x), fmaf(v1.y, rn, -l1.y),
                              fmaf(v1.z, rn, -l1.z), fmaf(v1.w, rn, -l1.w));
}

extern "C" void kernel_launch(void* const* d_in, const int* in_sizes, int n_in,
                              void* d_out, int out_size, void* d_ws, size_t ws_size,
                              hipStream_t stream) {
    const float* lc_x  = (const float*)d_in[0];   // 8*2048*64
    const float* knn_x = (const float*)d_in[1];   // 8*2048*32*6
    const float* fB    = (const float*)d_in[2];   // 7*32
    float* out = (float*)d_out;                   // 8*128*2048
    float* ws  = (float*)d_ws;                    // >= 512 floats

    hipMemsetAsync(d_ws, 0, 512 * sizeof(float), stream);

    void* args[] = { (void*)&lc_x, (void*)&knn_x, (void*)&fB,
                     (void*)&out, (void*)&ws };
    hipError_t err = hipLaunchCooperativeKernel(
        (const void*)line_fused, dim3(2048), dim3(256), args, 0, stream);
    if (err != hipSuccess) {
        (void)hipGetLastError();   // clear sticky error; use proven 2-kernel path
        line_pass1<<<2048, 256, 0, stream>>>(lc_x, knn_x, fB, out);
        line_pass2<<<512, 256, 0, stream>>>(out);
    }
}

// Round 13
// 19.911 us; speedup vs baseline: 19.2959x; 19.2959x over previous
//
#include <hip/hip_runtime.h>
#include <hip/hip_bf16.h>

// Problem constants: B=8, G=2048, K=32, N=6, C=64; fourier_B is (7,32)
// out: (B, 128, G) float32
//
// Algebraic simplifications (validated):
//  1) up/down == mean_k(knn_f) since e_x is constant over k, so
//     kl_raw = 2*mean_k(sin^5/cos^5(2*pi*x)).
//  2) x = fB . [p, p x n, p.n] is linear in p:
//     x = e0*p0 + e1*p1 + e2*p2 with per-channel e precomputed from fB and n.
//
// Round 13: LDS-pipe + VALU diet on the r9 skeleton (proven 21.5us).
//  - all 64 lanes gather p(bg=wave*2+half, k=jj) from global, write ONE packed
//    float4 to pbuf -> inner loop reads ONE uniform ds_read_b128 per k
//    (was 3x ds_read_b32): ~3x fewer LDS-pipe ops per wave.
//  - cos channel via v_cos_f32(fract(x)) (drops +0.25 add + second fract).
//  - rsq instead of 1/sqrt.
// Occupancy kept at 8 blocks/CU (2048 blocks; r7 showed 4 is too low).
// Grid-sync fusion abandoned: r12 measured ~350us for cg grid barrier.

#if __has_builtin(__builtin_amdgcn_fractf)
  #define FRACT(x) __builtin_amdgcn_fractf(x)
#else
  #define FRACT(x) ((x) - floorf(x))
#endif

__global__ __launch_bounds__(256, 8) void line_pass1(
    const float* __restrict__ lc_x,     // (B,G,64)
    const float* __restrict__ knn_x,    // (B,G,32,6)
    const float* __restrict__ fB,       // (7,32)
    float* __restrict__ out)            // (B,128,G)
{
    const int wave = threadIdx.x >> 6;
    const int lane = threadIdx.x & 63;
    const int half = lane >> 5;                 // 0: even k / bg i=0 gather
    const int jj   = lane & 31;                 // channel, and gather-k
    // bijective XCD swizzle: 2048 blocks, 8 XCDs, 256 blocks each
    const int sbid = (blockIdx.x & 7) * 256 + (blockIdx.x >> 3);
    const int bg0  = sbid * 8;                  // 8 consecutive bg per block
    const int b    = bg0 >> 11;
    const int g0   = bg0 & 2047;                // 8-aligned, never crosses b

    __shared__ __align__(16) float  lcbuf[4][128];   // [wave][2 rows x 64]
    __shared__ __align__(16) float4 pbuf[4][2][32];  // [wave][bg_i][k] packed p
    __shared__ float klbuf[128][9];                  // [channel][col], odd pad

    // fourier_B column for this lane's channel
    const float fb0 = fB[0*32 + jj];
    const float fb1 = fB[1*32 + jj];
    const float fb2 = fB[2*32 + jj];
    const float fb3 = fB[3*32 + jj];
    const float fb4 = fB[4*32 + jj];
    const float fb5 = fB[5*32 + jj];
    const float fb6 = fB[6*32 + jj];

    // ---- staging: lane (half,jj) gathers p for (bg = bg0+wave*2+half, k=jj);
    //      lanes<32 bulk-load the wave's 2 lc rows as float4.
    {
        const float* kp = knn_x + (size_t)(bg0 + wave * 2 + half) * 192 + jj * 6;
        const float gp0 = kp[3];
        const float gp1 = kp[4];
        const float gp2 = kp[5];
        float4 lcv;
        if (lane < 32)
            lcv = ((const float4*)(lc_x + (size_t)(bg0 + wave * 2) * 64))[lane];
        pbuf[wave][half][jj] = make_float4(gp0, gp1, gp2, 0.0f);  // coalesced b128
        if (lane < 32) ((float4*)&lcbuf[wave][0])[lane] = lcv;
    }
    // producer and consumer are the same wave -> wave-local wait, no barrier
    asm volatile("s_waitcnt lgkmcnt(0)" ::: "memory");

    #pragma unroll
    for (int i = 0; i < 2; ++i) {
        const int col = wave * 2 + i;
        const float* lcr = &lcbuf[wave][i * 64];

        // lc_normal = raw lc[3:6] (broadcast b32 reads)
        const float n0 = lcr[3];
        const float n1 = lcr[4];
        const float n2 = lcr[5];

        // lc_line: normalize over C=64
        const float myv = lcr[lane];
        float ssum = myv * myv;
        #pragma unroll
        for (int off = 32; off; off >>= 1) ssum += __shfl_xor(ssum, off, 64);
        klbuf[64 + lane][col] = myv * __builtin_amdgcn_rsqf(ssum);

        // effective projection vector: x = e0*p0 + e1*p1 + e2*p2
        const float e0 = fmaf(fb6, n0, fmaf(fb5,  n1, fmaf(fb4, -n2, fb0)));
        const float e1 = fmaf(fb6, n1, fmaf(fb5, -n0, fmaf(fb3,  n2, fb1)));
        const float e2 = fmaf(fb6, n2, fmaf(fb4,  n0, fmaf(fb3, -n1, fb2)));

        float accS0 = 0.f, accS1 = 0.f, accC0 = 0.f, accC1 = 0.f;
        const float4* myk = &pbuf[wave][i][half];       // k = 2*t + half
        #pragma unroll
        for (int t = 0; t < 16; ++t) {
            const float4 p = myk[2 * t];                // ONE uniform b128/iter
            const float x  = fmaf(e2, p.z, fmaf(e1, p.y, e0 * p.x));
            const float ts = FRACT(x);                  // revolutions [0,1)
            const float s  = __builtin_amdgcn_sinf(ts); // sin(2*pi*x)
            const float cq = __builtin_amdgcn_cosf(ts); // cos(2*pi*x)
            const float s2 = s * s,   s4 = s2 * s2;
            const float q2 = cq * cq, q4 = q2 * q2;
            if (t & 1) { accS1 = fmaf(s4, s, accS1); accC1 = fmaf(q4, cq, accC1); }
            else       { accS0 = fmaf(s4, s, accS0); accC0 = fmaf(q4, cq, accC0); }
        }
        // merge even-k / odd-k halves across the lane32 boundary
        const float aS = accS0 + accS1;
        const float aC = accC0 + accC1;
        const float totS = aS + __shfl_xor(aS, 32, 64);
        const float totC = aC + __shfl_xor(aC, 32, 64);
        klbuf[lane][col] = (half ? totC : totS) * 0.0625f;  // 2*mean_k
    }

    __syncthreads();

    // cooperative coalesced store: thread t -> row c=t>>1, cols (t&1)*4..+3
    const int c  = threadIdx.x >> 1;
    const int j0 = (threadIdx.x & 1) * 4;
    const float4 o = make_float4(klbuf[c][j0], klbuf[c][j0+1],
                                 klbuf[c][j0+2], klbuf[c][j0+3]);
    *(float4*)(out + ((size_t)b * 128 + c) * 2048 + g0 + j0) = o;
}

__global__ __launch_bounds__(256) void line_pass2(float* __restrict__ out)
{
    const int b = blockIdx.x >> 6;   // 0..7
    const int c = blockIdx.x & 63;   // 0..63
    float4*       kl = (float4*)(out + ((size_t)b * 128 + c) * 2048);
    const float4* ll = (const float4*)(out + ((size_t)b * 128 + 64 + c) * 2048);
    const int t = threadIdx.x;

    // issue ALL loads before the reduction so HBM latencies overlap
    const float4 v0 = kl[t];
    const float4 v1 = kl[t + 256];
    const float4 l0 = ll[t];
    const float4 l1 = ll[t + 256];

    float ss = v0.x*v0.x + v0.y*v0.y + v0.z*v0.z + v0.w*v0.w
             + v1.x*v1.x + v1.y*v1.y + v1.z*v1.z + v1.w*v1.w;
    #pragma unroll
    for (int off = 32; off; off >>= 1) ss += __shfl_xor(ss, off, 64);

    __shared__ float wsum[4];
    if ((t & 63) == 0) wsum[t >> 6] = ss;
    __syncthreads();
    const float tot = wsum[0] + wsum[1] + wsum[2] + wsum[3];
    const float rn  = __builtin_amdgcn_rsqf(tot);

    kl[t]       = make_float4(fmaf(v0.x, rn, -l0.x), fmaf(v0.y, rn, -l0.y),
                              fmaf(v0.z, rn, -l0.z), fmaf(v0.w, rn, -l0.w));
    kl[t + 256] = make_float4(fmaf(v1.x, rn, -l1.x), fmaf(v1.y, rn, -l1.y),
                              fmaf(v1.z, rn, -l1.z), fmaf(v1.w, rn, -l1.w));
}

extern "C" void kernel_launch(void* const* d_in, const int* in_sizes, int n_in,
                              void* d_out, int out_size, void* d_ws, size_t ws_size,
                              hipStream_t stream) {
    const float* lc_x  = (const float*)d_in[0];   // 8*2048*64
    const float* knn_x = (const float*)d_in[1];   // 8*2048*32*6
    const float* fB    = (const float*)d_in[2];   // 7*32
    float* out = (float*)d_out;                   // 8*128*2048

    line_pass1<<<2048, 256, 0, stream>>>(lc_x, knn_x, fB, out);
    line_pass2<<<512, 256, 0, stream>>>(out);
}

// Round 14
// 19.508 us; speedup vs baseline: 19.6941x; 1.0206x over previous
//
#include <hip/hip_runtime.h>
#include <hip/hip_bf16.h>

// Problem constants: B=8, G=2048, K=32, N=6, C=64; fourier_B is (7,32)
// out: (B, 128, G) float32
//
// Algebraic simplifications (validated):
//  1) up/down == mean_k(knn_f) since e_x is constant over k, so
//     kl_raw = 2*mean_k(sin^5/cos^5(2*pi*x)).
//  2) x = fB . [p, p x n, p.n] is linear in p:
//     x = e0*p0 + e1*p1 + e2*p2 with per-channel e precomputed from fB and n.
//
// Round 14 (on r13's 19.9us skeleton): move the norm reduction off the LDS
// pipe.
//  - 64-lane sum via DPP (row_shr:1/2/4/8 + row_bcast:15/31, 6 VALU adds)
//    + readlane(63) -> SGPR broadcast. Replaces 6 serial ds_swizzle ops/bg.
//  - lcbuf eliminated: myv loaded coalesced from global; n0..n2 via
//    readlane(myv, 3/4/5) (3 VALU/bg; r11's failure was 96 readlanes/bg).
//  - klbuf stays [128][9]: stride 9 is coprime with 32 banks (2-way max).
// LDS instrs/wave ~61 -> ~41; longest pass1 dependent chain now VALU-pipe.

#if __has_builtin(__builtin_amdgcn_fractf)
  #define FRACT(x) __builtin_amdgcn_fractf(x)
#else
  #define FRACT(x) ((x) - floorf(x))
#endif

__device__ __forceinline__ float rlanef(float v, int l) {
    return __int_as_float(__builtin_amdgcn_readlane(__float_as_int(v), l));
}

// Full-wave (64-lane) f32 sum via DPP; result returned as wave-uniform (SGPR).
__device__ __forceinline__ float wave_sum64(float v) {
    float s = v;
    s += __int_as_float(__builtin_amdgcn_update_dpp(
            0, __float_as_int(s), 0x111, 0xf, 0xf, true));  // row_shr:1
    s += __int_as_float(__builtin_amdgcn_update_dpp(
            0, __float_as_int(s), 0x112, 0xf, 0xf, true));  // row_shr:2
    s += __int_as_float(__builtin_amdgcn_update_dpp(
            0, __float_as_int(s), 0x114, 0xf, 0xf, true));  // row_shr:4
    s += __int_as_float(__builtin_amdgcn_update_dpp(
            0, __float_as_int(s), 0x118, 0xf, 0xf, true));  // row_shr:8
    s += __int_as_float(__builtin_amdgcn_update_dpp(
            0, __float_as_int(s), 0x142, 0xf, 0xf, true));  // row_bcast:15
    s += __int_as_float(__builtin_amdgcn_update_dpp(
            0, __float_as_int(s), 0x143, 0xf, 0xf, true));  // row_bcast:31
    return rlanef(s, 63);
}

__global__ __launch_bounds__(256, 8) void line_pass1(
    const float* __restrict__ lc_x,     // (B,G,64)
    const float* __restrict__ knn_x,    // (B,G,32,6)
    const float* __restrict__ fB,       // (7,32)
    float* __restrict__ out)            // (B,128,G)
{
    const int wave = threadIdx.x >> 6;
    const int lane = threadIdx.x & 63;
    const int half = lane >> 5;                 // staging: which bg; loop: k parity
    const int jj   = lane & 31;                 // channel, and gather-k
    // bijective XCD swizzle: 2048 blocks, 8 XCDs, 256 blocks each
    const int sbid = (blockIdx.x & 7) * 256 + (blockIdx.x >> 3);
    const int bg0  = sbid * 8;                  // 8 consecutive bg per block
    const int b    = bg0 >> 11;
    const int g0   = bg0 & 2047;                // 8-aligned, never crosses b

    __shared__ __align__(16) float4 pbuf[4][2][32];  // [wave][bg_i][k] packed p
    __shared__ float klbuf[128][9];                  // [channel][col], odd pad

    // fourier_B column for this lane's channel
    const float fb0 = fB[0*32 + jj];
    const float fb1 = fB[1*32 + jj];
    const float fb2 = fB[2*32 + jj];
    const float fb3 = fB[3*32 + jj];
    const float fb4 = fB[4*32 + jj];
    const float fb5 = fB[5*32 + jj];
    const float fb6 = fB[6*32 + jj];

    // ---- global loads issued up front (coalesced lc; strided p gather)
    const int bgw = bg0 + wave * 2;
    const float myv0 = lc_x[(size_t)bgw * 64 + lane];
    const float myv1 = lc_x[(size_t)(bgw + 1) * 64 + lane];
    {
        const float* kp = knn_x + (size_t)(bgw + half) * 192 + jj * 6;
        pbuf[wave][half][jj] = make_float4(kp[3], kp[4], kp[5], 0.0f);
    }
    // producer and consumer are the same wave -> wave-local wait, no barrier
    asm volatile("s_waitcnt lgkmcnt(0)" ::: "memory");

    #pragma unroll
    for (int i = 0; i < 2; ++i) {
        const int col = wave * 2 + i;
        const float myv = (i == 0) ? myv0 : myv1;

        // lc_normal = lc[3:6] via register broadcast (VALU, no LDS)
        const float n0 = rlanef(myv, 3);
        const float n1 = rlanef(myv, 4);
        const float n2 = rlanef(myv, 5);

        // lc_line: normalize over C=64 (DPP reduce, VALU-pipe only)
        const float ssum = wave_sum64(myv * myv);
        klbuf[64 + lane][col] = myv * __builtin_amdgcn_rsqf(ssum);

        // effective projection vector: x = e0*p0 + e1*p1 + e2*p2
        const float e0 = fmaf(fb6, n0, fmaf(fb5,  n1, fmaf(fb4, -n2, fb0)));
        const float e1 = fmaf(fb6, n1, fmaf(fb5, -n0, fmaf(fb3,  n2, fb1)));
        const float e2 = fmaf(fb6, n2, fmaf(fb4,  n0, fmaf(fb3, -n1, fb2)));

        float accS0 = 0.f, accS1 = 0.f, accC0 = 0.f, accC1 = 0.f;
        const float4* myk = &pbuf[wave][i][half];       // k = 2*t + half
        #pragma unroll
        for (int t = 0; t < 16; ++t) {
            const float4 p = myk[2 * t];                // ONE uniform b128/iter
            const float x  = fmaf(e2, p.z, fmaf(e1, p.y, e0 * p.x));
            const float ts = FRACT(x);                  // revolutions [0,1)
            const float s  = __builtin_amdgcn_sinf(ts); // sin(2*pi*x)
            const float cq = __builtin_amdgcn_cosf(ts); // cos(2*pi*x)
            const float s2 = s * s,   s4 = s2 * s2;
            const float q2 = cq * cq, q4 = q2 * q2;
            if (t & 1) { accS1 = fmaf(s4, s, accS1); accC1 = fmaf(q4, cq, accC1); }
            else       { accS0 = fmaf(s4, s, accS0); accC0 = fmaf(q4, cq, accC0); }
        }
        // merge even-k / odd-k halves across the lane32 boundary
        const float aS = accS0 + accS1;
        const float aC = accC0 + accC1;
        const float totS = aS + __shfl_xor(aS, 32, 64);
        const float totC = aC + __shfl_xor(aC, 32, 64);
        klbuf[lane][col] = (half ? totC : totS) * 0.0625f;  // 2*mean_k
    }

    __syncthreads();

    // cooperative coalesced store: thread t -> row c=t>>1, cols (t&1)*4..+3
    const int c  = threadIdx.x >> 1;
    const int j0 = (threadIdx.x & 1) * 4;
    const float4 o = make_float4(klbuf[c][j0], klbuf[c][j0+1],
                                 klbuf[c][j0+2], klbuf[c][j0+3]);
    *(float4*)(out + ((size_t)b * 128 + c) * 2048 + g0 + j0) = o;
}

__global__ __launch_bounds__(256) void line_pass2(float* __restrict__ out)
{
    const int b = blockIdx.x >> 6;   // 0..7
    const int c = blockIdx.x & 63;   // 0..63
    float4*       kl = (float4*)(out + ((size_t)b * 128 + c) * 2048);
    const float4* ll = (const float4*)(out + ((size_t)b * 128 + 64 + c) * 2048);
    const int t = threadIdx.x;

    // issue ALL loads before the reduction so HBM latencies overlap
    const float4 v0 = kl[t];
    const float4 v1 = kl[t + 256];
    const float4 l0 = ll[t];
    const float4 l1 = ll[t + 256];

    float ss = v0.x*v0.x + v0.y*v0.y + v0.z*v0.z + v0.w*v0.w
             + v1.x*v1.x + v1.y*v1.y + v1.z*v1.z + v1.w*v1.w;
    #pragma unroll
    for (int off = 32; off; off >>= 1) ss += __shfl_xor(ss, off, 64);

    __shared__ float wsum[4];
    if ((t & 63) == 0) wsum[t >> 6] = ss;
    __syncthreads();
    const float tot = wsum[0] + wsum[1] + wsum[2] + wsum[3];
    const float rn  = __builtin_amdgcn_rsqf(tot);

    kl[t]       = make_float4(fmaf(v0.x, rn, -l0.x), fmaf(v0.y, rn, -l0.y),
                              fmaf(v0.z, rn, -l0.z), fmaf(v0.w, rn, -l0.w));
    kl[t + 256] = make_float4(fmaf(v1.x, rn, -l1.x), fmaf(v1.y, rn, -l1.y),
                              fmaf(v1.z, rn, -l1.z), fmaf(v1.w, rn, -l1.w));
}

extern "C" void kernel_launch(void* const* d_in, const int* in_sizes, int n_in,
                              void* d_out, int out_size, void* d_ws, size_t ws_size,
                              hipStream_t stream) {
    const float* lc_x  = (const float*)d_in[0];   // 8*2048*64
    const float* knn_x = (const float*)d_in[1];   // 8*2048*32*6
    const float* fB    = (const float*)d_in[2];   // 7*32
    float* out = (float*)d_out;                   // 8*128*2048

    line_pass1<<<2048, 256, 0, stream>>>(lc_x, knn_x, fB, out);
    line_pass2<<<512, 256, 0, stream>>>(out);
}